// Round 3
// baseline (151.910 us; speedup 1.0000x reference)
//
#include <hip/hip_runtime.h>

#define N_NODES 2048
#define F_IN    2048
#define G1      10
#define NCLS    10
#define NEDGE   65536
#define JCHUNKS 32
#define JPER    (F_IN / JCHUNKS)   // 64 K-elements per chunk

// All intermediates in the .so's device data segment — no ws_size dependence.
// Re-initialized every call by k_zero (g_p is fully overwritten, no init).
__device__ int   g_deg[N_NODES];
__device__ float g_p[JCHUNKS * 20 * N_NODES]; // [jc][k][row] split-K partials
__device__ float g_y[N_NODES * 20];           // [row][k] : k<10 -> x@W0, k>=10 -> x@W1
__device__ float g_z[N_NODES * G1];           // scattered Tx1@W1

// zero accumulators (grid: 40960 threads)
__global__ __launch_bounds__(256) void k_zero() {
    int t = blockIdx.x * 256 + threadIdx.x;
    g_y[t] = 0.f;                        // t < 40960 exactly
    if (t < N_NODES * G1) g_z[t] = 0.f;
    if (t < N_NODES)      g_deg[t] = 0;
}

// degree histogram over row = edge_index[0]
__global__ __launch_bounds__(256) void k_deg(const int* __restrict__ ei) {
    int t = blockIdx.x * 256 + threadIdx.x;
    atomicAdd(&g_deg[ei[t]], 1);         // grid == NEDGE threads exactly
}

// split-K GEMM: p[jc][k][row] = sum_{j in chunk jc} x[row][j] * [W0|W1][j][k]
// blockIdx.x = K-chunk, blockIdx.y*256+tid = row. W addresses are block/loop-
// uniform -> scalar loads; x read as float4 (16B/lane); stores lane-coalesced.
__global__ __launch_bounds__(256) void k_gemm(const float* __restrict__ x,
                                              const float* __restrict__ W0,
                                              const float* __restrict__ W1) {
    int jc  = blockIdx.x;
    int row = blockIdx.y * 256 + threadIdx.x;
    int j0  = jc * JPER;
    float acc[20];
    #pragma unroll
    for (int k = 0; k < 20; ++k) acc[k] = 0.f;

    const float4* xr = (const float4*)(x + (size_t)row * F_IN + j0);
    #pragma unroll 4
    for (int jj = 0; jj < JPER / 4; ++jj) {
        float4 v = xr[jj];
        float xs[4] = {v.x, v.y, v.z, v.w};
        int jb = j0 + jj * 4;
        #pragma unroll
        for (int u = 0; u < 4; ++u) {
            const float* w0r = W0 + (size_t)(jb + u) * G1;  // uniform -> s_load
            const float* w1r = W1 + (size_t)(jb + u) * G1;  // uniform -> s_load
            float xu = xs[u];
            #pragma unroll
            for (int k = 0; k < G1; ++k) {
                acc[k]      += xu * w0r[k];
                acc[10 + k] += xu * w1r[k];
            }
        }
    }
    #pragma unroll
    for (int k = 0; k < 20; ++k)
        g_p[((size_t)jc * 20 + k) * N_NODES + row] = acc[k];
}

// reduce split-K partials -> g_y[row*20+k]; reads coalesced (row contiguous)
__global__ __launch_bounds__(256) void k_reduce() {
    int t   = blockIdx.x * 256 + threadIdx.x;  // < 40960
    int k   = t >> 11;                         // 0..19
    int row = t & (N_NODES - 1);
    float s = 0.f;
    #pragma unroll 8
    for (int jc = 0; jc < JCHUNKS; ++jc)
        s += g_p[((size_t)jc * 20 + k) * N_NODES + row];
    g_y[row * 20 + k] = s;
}

// z[col][:] += w_e * (x@W1)[row][:],  w_e = -rsqrt(deg[row])*rsqrt(deg[col])
// (scatter commuted past the skinny matmul: E*G1 instead of E*F_IN work)
__global__ __launch_bounds__(256) void k_scatter(const int* __restrict__ ei) {
    int e = blockIdx.x * 256 + threadIdx.x;
    int r = ei[e], c = ei[NEDGE + e];
    int dr = g_deg[r], dc = g_deg[c];
    if (dr > 0 && dc > 0) {
        float w = -rsqrtf((float)dr) * rsqrtf((float)dc);
        const float* y1 = g_y + r * 20 + 10;
        float* zz = g_z + c * 10;
        #pragma unroll
        for (int k = 0; k < G1; ++k) atomicAdd(&zz[k], w * y1[k]);
    }
}

// per node: h = relu(x@W0 + z + b); logits = h@Wf + bf; log_softmax
__global__ __launch_bounds__(256) void k_final(const float* __restrict__ b,
                                               const float* __restrict__ Wf,
                                               const float* __restrict__ bfv,
                                               float* __restrict__ out) {
    int i = blockIdx.x * 256 + threadIdx.x;   // grid == N_NODES exactly
    float h[G1];
    #pragma unroll
    for (int k = 0; k < G1; ++k)
        h[k] = fmaxf(g_y[i * 20 + k] + g_z[i * 10 + k] + b[k], 0.f);
    float lo[NCLS];
    #pragma unroll
    for (int c = 0; c < NCLS; ++c) lo[c] = bfv[c];
    #pragma unroll
    for (int k = 0; k < G1; ++k) {
        float hk = h[k];
        #pragma unroll
        for (int c = 0; c < NCLS; ++c) lo[c] += hk * Wf[k * NCLS + c];
    }
    float m = lo[0];
    #pragma unroll
    for (int c = 1; c < NCLS; ++c) m = fmaxf(m, lo[c]);
    float s = 0.f;
    #pragma unroll
    for (int c = 0; c < NCLS; ++c) s += expf(lo[c] - m);
    float ls = logf(s);
    #pragma unroll
    for (int c = 0; c < NCLS; ++c) out[i * NCLS + c] = lo[c] - m - ls;
}

extern "C" void kernel_launch(void* const* d_in, const int* in_sizes, int n_in,
                              void* d_out, int out_size, void* d_ws, size_t ws_size,
                              hipStream_t stream) {
    const float* x   = (const float*)d_in[0];
    const int*   ei  = (const int*)d_in[1];
    const float* W0  = (const float*)d_in[2];
    const float* W1  = (const float*)d_in[3];
    const float* b   = (const float*)d_in[4];
    const float* Wf  = (const float*)d_in[5];
    const float* bfv = (const float*)d_in[6];
    float* out = (float*)d_out;

    k_zero<<<(N_NODES * 20) / 256, 256, 0, stream>>>();
    k_deg<<<NEDGE / 256, 256, 0, stream>>>(ei);
    k_gemm<<<dim3(JCHUNKS, N_NODES / 256), 256, 0, stream>>>(x, W0, W1);
    k_reduce<<<(N_NODES * 20) / 256, 256, 0, stream>>>();
    k_scatter<<<NEDGE / 256, 256, 0, stream>>>(ei);
    k_final<<<N_NODES / 256, 256, 0, stream>>>(b, Wf, bfv, out);
}

// Round 4
// 143.802 us; speedup vs baseline: 1.0564x; 1.0564x over previous
//
#include <hip/hip_runtime.h>

#define N_NODES 2048
#define F_IN    2048
#define G1      10
#define NCLS    10
#define NEDGE   65536
#define JCHUNKS 64
#define JPER    (F_IN / JCHUNKS)     // 32 K-elements per chunk
#define HSLICES 32                   // histogram edge slices
#define ZSLICES 32                   // scatter edge slices (x2 k-halves)

// Device-global intermediates (bss of the .so). Every buffer is fully
// overwritten each call — no zero-init kernel, no cross-call state.
__device__ float g_p[JCHUNKS * 20 * N_NODES];       // [jc][k][row] GEMM split-K partials
__device__ int   g_degp[HSLICES * N_NODES];         // per-slice degree histograms
__device__ float g_dis[N_NODES];                    // deg>0 ? rsqrt(deg) : 0
__device__ float g_y[N_NODES * 20];                 // [row][k]: k<10 x@W0, k>=10 x@W1
__device__ float g_zp[2 * ZSLICES * N_NODES * 5];   // [khalf][slice][c*5+kk] z partials

// ---- 1) degree histogram, LDS-privatized (no global atomics) ----
__global__ __launch_bounds__(256) void k_hist(const int* __restrict__ ei) {
    __shared__ int h[N_NODES];
    for (int t = threadIdx.x; t < N_NODES; t += 256) h[t] = 0;
    __syncthreads();
    int base = blockIdx.x * (NEDGE / HSLICES);
    #pragma unroll
    for (int u = 0; u < NEDGE / HSLICES / 256; ++u)
        atomicAdd(&h[ei[base + u * 256 + threadIdx.x]], 1);
    __syncthreads();
    for (int t = threadIdx.x; t < N_NODES; t += 256)
        g_degp[blockIdx.x * N_NODES + t] = h[t];
}

// ---- 2) split-K GEMM: p[jc][k][row] = sum_{j in chunk} x[row][j]*[W0|W1][j][k]
// W addresses are block/loop-uniform -> s_load; x read as float4; stores coalesced.
__global__ __launch_bounds__(256) void k_gemm(const float* __restrict__ x,
                                              const float* __restrict__ W0,
                                              const float* __restrict__ W1) {
    int jc  = blockIdx.x;
    int row = blockIdx.y * 256 + threadIdx.x;
    int j0  = jc * JPER;
    float acc[20];
    #pragma unroll
    for (int k = 0; k < 20; ++k) acc[k] = 0.f;

    const float4* xr = (const float4*)(x + (size_t)row * F_IN + j0);
    #pragma unroll
    for (int jj = 0; jj < JPER / 4; ++jj) {
        float4 v = xr[jj];
        float xs[4] = {v.x, v.y, v.z, v.w};
        int jb = j0 + jj * 4;
        #pragma unroll
        for (int u = 0; u < 4; ++u) {
            const float* w0r = W0 + (size_t)(jb + u) * G1;   // uniform -> s_load
            const float* w1r = W1 + (size_t)(jb + u) * G1;   // uniform -> s_load
            float xu = xs[u];
            #pragma unroll
            for (int k = 0; k < G1; ++k) {
                acc[k]      += xu * w0r[k];
                acc[10 + k] += xu * w1r[k];
            }
        }
    }
    #pragma unroll
    for (int k = 0; k < 20; ++k)
        g_p[((size_t)jc * 20 + k) * N_NODES + row] = acc[k];
}

// ---- 3) reduce GEMM partials -> g_y ; reduce degree partials -> g_dis ----
__global__ __launch_bounds__(256) void k_reduce() {
    int t   = blockIdx.x * 256 + threadIdx.x;   // < 40960
    int k   = t >> 11;
    int row = t & (N_NODES - 1);
    float s = 0.f;
    #pragma unroll
    for (int jc = 0; jc < JCHUNKS; ++jc)
        s += g_p[((size_t)jc * 20 + k) * N_NODES + row];
    g_y[row * 20 + k] = s;
    if (t < N_NODES) {
        int d = 0;
        #pragma unroll
        for (int sl = 0; sl < HSLICES; ++sl) d += g_degp[sl * N_NODES + t];
        g_dis[t] = (d > 0) ? rsqrtf((float)d) : 0.f;
    }
}

// ---- 4) edge scatter in projected space, LDS-privatized half-z per block ----
// blockIdx: slice = b&31 (edge range), khalf = b>>5 (k in [khalf*5, khalf*5+5)).
__global__ __launch_bounds__(256) void k_scatter(const int* __restrict__ ei) {
    __shared__ float zl[N_NODES * 5];            // 40 KB
    int bslice = blockIdx.x & (ZSLICES - 1);
    int khalf  = blockIdx.x >> 5;
    for (int t = threadIdx.x; t < N_NODES * 5; t += 256) zl[t] = 0.f;
    __syncthreads();
    int base = bslice * (NEDGE / ZSLICES);
    #pragma unroll
    for (int u = 0; u < NEDGE / ZSLICES / 256; ++u) {
        int e = base + u * 256 + threadIdx.x;
        int r = ei[e], c = ei[NEDGE + e];
        float w = -g_dis[r] * g_dis[c];          // 0 if either deg==0
        const float* y1 = g_y + r * 20 + 10 + khalf * 5;
        float* zz = zl + c * 5;
        #pragma unroll
        for (int kk = 0; kk < 5; ++kk) atomicAdd(&zz[kk], w * y1[kk]);
    }
    __syncthreads();
    float* dst = g_zp + ((size_t)khalf * ZSLICES + bslice) * (N_NODES * 5);
    for (int t = threadIdx.x; t < N_NODES * 5; t += 256) dst[t] = zl[t];
}

// ---- 5) epilogue: reduce z partials + relu(y0+z+b) @ Wf + log_softmax ----
__global__ __launch_bounds__(256) void k_final(const float* __restrict__ b,
                                               const float* __restrict__ Wf,
                                               const float* __restrict__ bfv,
                                               float* __restrict__ out) {
    int i = blockIdx.x * 256 + threadIdx.x;      // grid == N_NODES exactly
    float h[G1];
    #pragma unroll
    for (int k = 0; k < G1; ++k) {
        int khalf = k / 5, kk = k % 5;
        float z = 0.f;
        #pragma unroll
        for (int sl = 0; sl < ZSLICES; ++sl)
            z += g_zp[((size_t)khalf * ZSLICES + sl) * (N_NODES * 5) + i * 5 + kk];
        h[k] = fmaxf(g_y[i * 20 + k] + z + b[k], 0.f);
    }
    float lo[NCLS];
    #pragma unroll
    for (int c = 0; c < NCLS; ++c) lo[c] = bfv[c];
    #pragma unroll
    for (int k = 0; k < G1; ++k) {
        float hk = h[k];
        #pragma unroll
        for (int c = 0; c < NCLS; ++c) lo[c] += hk * Wf[k * NCLS + c];
    }
    float m = lo[0];
    #pragma unroll
    for (int c = 1; c < NCLS; ++c) m = fmaxf(m, lo[c]);
    float s = 0.f;
    #pragma unroll
    for (int c = 0; c < NCLS; ++c) s += expf(lo[c] - m);
    float ls = logf(s);
    #pragma unroll
    for (int c = 0; c < NCLS; ++c) out[i * NCLS + c] = lo[c] - m - ls;
}

extern "C" void kernel_launch(void* const* d_in, const int* in_sizes, int n_in,
                              void* d_out, int out_size, void* d_ws, size_t ws_size,
                              hipStream_t stream) {
    const float* x   = (const float*)d_in[0];
    const int*   ei  = (const int*)d_in[1];
    const float* W0  = (const float*)d_in[2];
    const float* W1  = (const float*)d_in[3];
    const float* b   = (const float*)d_in[4];
    const float* Wf  = (const float*)d_in[5];
    const float* bfv = (const float*)d_in[6];
    float* out = (float*)d_out;

    k_hist<<<HSLICES, 256, 0, stream>>>(ei);
    k_gemm<<<dim3(JCHUNKS, N_NODES / 256), 256, 0, stream>>>(x, W0, W1);
    k_reduce<<<(N_NODES * 20) / 256, 256, 0, stream>>>();
    k_scatter<<<2 * ZSLICES, 256, 0, stream>>>(ei);
    k_final<<<N_NODES / 256, 256, 0, stream>>>(b, Wf, bfv, out);
}

// Round 5
// 113.537 us; speedup vs baseline: 1.3380x; 1.2666x over previous
//
#include <hip/hip_runtime.h>

#define N_NODES 2048
#define F_IN    2048
#define G1      10
#define NCLS    10
#define NEDGE   65536
#define JCHUNKS 64
#define JPER    32                   // K-elements per chunk
#define HSLICES 128                  // histogram edge slices
#define ZSLICES 128                  // scatter edge slices per k-half

// Device-global intermediates (bss of the .so) — fully overwritten each call.
__device__ float g_p[JCHUNKS * 20 * N_NODES];       // [jc][k][row] split-K partials (10.5 MB)
__device__ int   g_degp[HSLICES * N_NODES];         // per-slice degree histograms (1 MB)
__device__ float g_dis[N_NODES];                    // deg>0 ? rsqrt(deg) : 0
__device__ float g_y[N_NODES * 20];                 // [row][k]: k<10 x@W0, k>=10 x@W1
__device__ float g_zp[2 * ZSLICES * N_NODES * 5];   // [khalf][slice][i*5+kk] (10.5 MB)
__device__ float g_z[N_NODES * G1];                 // reduced Tx1@W1 scatter

// ---- 1) degree histogram, LDS-privatized, 128 blocks ----
__global__ __launch_bounds__(256) void k_hist(const int* __restrict__ ei) {
    __shared__ int h[N_NODES];
    for (int t = threadIdx.x; t < N_NODES; t += 256) h[t] = 0;
    __syncthreads();
    int base = blockIdx.x * (NEDGE / HSLICES);
    #pragma unroll
    for (int u = 0; u < NEDGE / HSLICES / 256; ++u)
        atomicAdd(&h[ei[base + u * 256 + threadIdx.x]], 1);
    __syncthreads();
    for (int t = threadIdx.x; t < N_NODES; t += 256)
        g_degp[blockIdx.x * N_NODES + t] = h[t];
}

// ---- 2) split-K GEMM, LDS-staged coalesced x loads ----
// Tile: 256 rows x 32 cols. Global: 128B segments. LDS stride 33 -> lane-
// distinct banks on read (2 lanes/bank = free). W rows are loop-uniform -> s_load.
__global__ __launch_bounds__(256) void k_gemm(const float* __restrict__ x,
                                              const float* __restrict__ W0,
                                              const float* __restrict__ W1) {
    __shared__ float sx[256 * 33];   // 33.8 KB
    int jc      = blockIdx.x;
    int rowbase = blockIdx.y * 256;
    int j0      = jc * JPER;

    #pragma unroll
    for (int rep = 0; rep < 8; ++rep) {
        int idx = rep * 256 + threadIdx.x;
        int r = idx >> 3, c4 = idx & 7;
        float4 v = *(const float4*)(x + (size_t)(rowbase + r) * F_IN + j0 + c4 * 4);
        float* d = sx + r * 33 + c4 * 4;
        d[0] = v.x; d[1] = v.y; d[2] = v.z; d[3] = v.w;
    }
    __syncthreads();

    float acc[20];
    #pragma unroll
    for (int k = 0; k < 20; ++k) acc[k] = 0.f;

    const float* xr = sx + threadIdx.x * 33;
    #pragma unroll
    for (int j = 0; j < JPER; ++j) {
        float xu = xr[j];
        const float* w0r = W0 + (size_t)(j0 + j) * G1;  // uniform -> s_load
        const float* w1r = W1 + (size_t)(j0 + j) * G1;
        #pragma unroll
        for (int k = 0; k < G1; ++k) {
            acc[k]      += xu * w0r[k];
            acc[10 + k] += xu * w1r[k];
        }
    }
    int row = rowbase + threadIdx.x;
    #pragma unroll
    for (int k = 0; k < 20; ++k)
        g_p[((size_t)jc * 20 + k) * N_NODES + row] = acc[k];   // coalesced
}

// ---- 3) reduce GEMM partials -> g_y ; degree partials -> g_dis ----
__global__ __launch_bounds__(256) void k_reduce() {
    int t   = blockIdx.x * 256 + threadIdx.x;   // < 40960
    int k   = t >> 11;
    int row = t & (N_NODES - 1);
    float s = 0.f;
    #pragma unroll 16
    for (int jc = 0; jc < JCHUNKS; ++jc)
        s += g_p[((size_t)jc * 20 + k) * N_NODES + row];
    g_y[row * 20 + k] = s;
    if (t < N_NODES) {
        int d = 0;
        #pragma unroll 16
        for (int sl = 0; sl < HSLICES; ++sl) d += g_degp[sl * N_NODES + t];
        g_dis[t] = (d > 0) ? rsqrtf((float)d) : 0.f;
    }
}

// ---- 4) edge scatter in projected space, LDS-privatized, 256 blocks ----
// blockIdx: slice = b&127 (512 edges), khalf = b>>7 (k in [khalf*5, khalf*5+5)).
__global__ __launch_bounds__(256) void k_scatter(const int* __restrict__ ei) {
    __shared__ float zl[N_NODES * 5];            // 40 KB
    int bslice = blockIdx.x & (ZSLICES - 1);
    int khalf  = blockIdx.x >> 7;
    for (int t = threadIdx.x; t < N_NODES * 5; t += 256) zl[t] = 0.f;
    __syncthreads();
    int base = bslice * (NEDGE / ZSLICES);
    #pragma unroll
    for (int u = 0; u < NEDGE / ZSLICES / 256; ++u) {
        int e = base + u * 256 + threadIdx.x;
        int r = ei[e], c = ei[NEDGE + e];
        float w = -g_dis[r] * g_dis[c];          // 0 if either deg==0
        const float* y1 = g_y + r * 20 + 10 + khalf * 5;
        float* zz = zl + c * 5;
        #pragma unroll
        for (int kk = 0; kk < 5; ++kk) atomicAdd(&zz[kk], w * y1[kk]);
    }
    __syncthreads();
    float* dst = g_zp + ((size_t)khalf * ZSLICES + bslice) * (N_NODES * 5);
    for (int t = threadIdx.x; t < N_NODES * 5; t += 256) dst[t] = zl[t];
}

// ---- 5) coalesced z-partial reduction -> g_z[node][k] ----
__global__ __launch_bounds__(256) void k_zred() {
    int t = blockIdx.x * 256 + threadIdx.x;      // < 20480
    int khalf = t / (N_NODES * 5);
    int rem   = t % (N_NODES * 5);
    float s = 0.f;
    #pragma unroll 16
    for (int sl = 0; sl < ZSLICES; ++sl)
        s += g_zp[((size_t)khalf * ZSLICES + sl) * (N_NODES * 5) + rem];
    int i = rem / 5, kk = rem - i * 5;
    g_z[i * 10 + khalf * 5 + kk] = s;
}

// ---- 6) epilogue: relu(y0+z+b) @ Wf + log_softmax ----
__global__ __launch_bounds__(256) void k_final(const float* __restrict__ b,
                                               const float* __restrict__ Wf,
                                               const float* __restrict__ bfv,
                                               float* __restrict__ out) {
    int i = blockIdx.x * 256 + threadIdx.x;      // grid == N_NODES exactly
    float h[G1];
    #pragma unroll
    for (int k = 0; k < G1; ++k)
        h[k] = fmaxf(g_y[i * 20 + k] + g_z[i * 10 + k] + b[k], 0.f);
    float lo[NCLS];
    #pragma unroll
    for (int c = 0; c < NCLS; ++c) lo[c] = bfv[c];
    #pragma unroll
    for (int k = 0; k < G1; ++k) {
        float hk = h[k];
        #pragma unroll
        for (int c = 0; c < NCLS; ++c) lo[c] += hk * Wf[k * NCLS + c];
    }
    float m = lo[0];
    #pragma unroll
    for (int c = 1; c < NCLS; ++c) m = fmaxf(m, lo[c]);
    float s = 0.f;
    #pragma unroll
    for (int c = 0; c < NCLS; ++c) s += expf(lo[c] - m);
    float ls = logf(s);
    #pragma unroll
    for (int c = 0; c < NCLS; ++c) out[i * NCLS + c] = lo[c] - m - ls;
}

extern "C" void kernel_launch(void* const* d_in, const int* in_sizes, int n_in,
                              void* d_out, int out_size, void* d_ws, size_t ws_size,
                              hipStream_t stream) {
    const float* x   = (const float*)d_in[0];
    const int*   ei  = (const int*)d_in[1];
    const float* W0  = (const float*)d_in[2];
    const float* W1  = (const float*)d_in[3];
    const float* b   = (const float*)d_in[4];
    const float* Wf  = (const float*)d_in[5];
    const float* bfv = (const float*)d_in[6];
    float* out = (float*)d_out;

    k_hist<<<HSLICES, 256, 0, stream>>>(ei);
    k_gemm<<<dim3(JCHUNKS, N_NODES / 256), 256, 0, stream>>>(x, W0, W1);
    k_reduce<<<(N_NODES * 20) / 256, 256, 0, stream>>>();
    k_scatter<<<2 * ZSLICES, 256, 0, stream>>>(ei);
    k_zred<<<(2 * ZSLICES * 0 + N_NODES * G1) / 256, 256, 0, stream>>>();
    k_final<<<N_NODES / 256, 256, 0, stream>>>(b, Wf, bfv, out);
}

// Round 6
// 110.765 us; speedup vs baseline: 1.3715x; 1.0250x over previous
//
#include <hip/hip_runtime.h>

#define N_NODES 2048
#define F_IN    2048
#define G1      10
#define NCLS    10
#define NEDGE   65536
#define JCHUNKS 64
#define JPER    32                   // K-elements per chunk
#define HSLICES 128                  // histogram edge slices (fused into k_gemm)
#define ZSLICES 64                   // scatter edge slices per k-half

// Device-global intermediates (bss of the .so) — fully overwritten each call.
__device__ float g_p[JCHUNKS * 20 * N_NODES];       // [jc][k][row] split-K partials (10.5 MB)
__device__ int   g_degp[HSLICES * N_NODES];         // per-slice degree histograms (1 MB)
__device__ float g_dis[N_NODES];                    // deg>0 ? rsqrt(deg) : 0
__device__ float g_y[N_NODES * 20];                 // [row][k]: k<10 x@W0, k>=10 x@W1
__device__ float g_zp[2 * ZSLICES * N_NODES * 5];   // [khalf][slice][i*5+kk] (5.25 MB)
__device__ float g_z[N_NODES * G1];                 // reduced Tx1@W1 scatter

// ---- 1) split-K GEMM (LDS-staged coalesced x) + fused degree histogram ----
// Tile: 256 rows x 32 cols. LDS stride 33 -> 2 lanes/bank on read (free).
// W rows loop-uniform -> s_load broadcast. Blocks with by<4 redo the degree
// histogram afterwards, reusing the x-tile LDS as an int scratch.
__global__ __launch_bounds__(256) void k_gemm(const float* __restrict__ x,
                                              const float* __restrict__ W0,
                                              const float* __restrict__ W1,
                                              const int* __restrict__ ei) {
    __shared__ float sx[256 * 33];   // 33.8 KB
    int jc      = blockIdx.x;
    int rowbase = blockIdx.y * 256;
    int j0      = jc * JPER;

    #pragma unroll
    for (int rep = 0; rep < 8; ++rep) {
        int idx = rep * 256 + threadIdx.x;
        int r = idx >> 3, c4 = idx & 7;
        float4 v = *(const float4*)(x + (size_t)(rowbase + r) * F_IN + j0 + c4 * 4);
        float* d = sx + r * 33 + c4 * 4;
        d[0] = v.x; d[1] = v.y; d[2] = v.z; d[3] = v.w;
    }
    __syncthreads();

    float acc[20];
    #pragma unroll
    for (int k = 0; k < 20; ++k) acc[k] = 0.f;

    const float* xr = sx + threadIdx.x * 33;
    #pragma unroll
    for (int j = 0; j < JPER; ++j) {
        float xu = xr[j];
        const float* w0r = W0 + (size_t)(j0 + j) * G1;  // uniform -> s_load
        const float* w1r = W1 + (size_t)(j0 + j) * G1;
        #pragma unroll
        for (int k = 0; k < G1; ++k) {
            acc[k]      += xu * w0r[k];
            acc[10 + k] += xu * w1r[k];
        }
    }
    int row = rowbase + threadIdx.x;
    #pragma unroll
    for (int k = 0; k < 20; ++k)
        g_p[((size_t)jc * 20 + k) * N_NODES + row] = acc[k];   // coalesced

    // fused histogram: 128 of 512 blocks, 512 edges each (block-uniform branch)
    if (blockIdx.y < 4) {
        int hs = blockIdx.y * JCHUNKS + jc;        // 0..127... wait: by<4, jc<64 -> by*64+jc? see below
        hs = blockIdx.y * 64 + jc;                 // 0..255? no: by in 0..3 -> need *32? fix: use by*32 invalid.
        hs = (blockIdx.y << 5) * 2 + jc;           // == by*64+jc, 0..255 — mask to 128 below
        hs = blockIdx.y * 32 + (jc & 31);          // FINAL: 0..127, jc>=32 unused? no — see guard
        // Simpler correct mapping: slices 0..127 handled by (by*32 + jc) for jc<32 only.
        if (jc < 32) {
            int slice = blockIdx.y * 32 + jc;      // 0..127
            __syncthreads();
            int* h = (int*)sx;
            #pragma unroll
            for (int t = threadIdx.x; t < N_NODES; t += 256) h[t] = 0;
            __syncthreads();
            int base = slice * (NEDGE / HSLICES);  // 512 edges per slice
            #pragma unroll
            for (int u = 0; u < 2; ++u)
                atomicAdd(&h[ei[base + u * 256 + threadIdx.x]], 1);
            __syncthreads();
            #pragma unroll
            for (int t = threadIdx.x; t < N_NODES; t += 256)
                g_degp[slice * N_NODES + t] = h[t];
        }
    }
}

// ---- 2) reduce GEMM partials -> g_y ; degree partials -> g_dis ----
__global__ __launch_bounds__(256) void k_reduce() {
    int t   = blockIdx.x * 256 + threadIdx.x;   // 160 blocks -> t < 40960
    int k   = t >> 11;
    int row = t & (N_NODES - 1);
    float s = 0.f;
    #pragma unroll 16
    for (int jc = 0; jc < JCHUNKS; ++jc)
        s += g_p[((size_t)jc * 20 + k) * N_NODES + row];
    g_y[row * 20 + k] = s;
    if (t < N_NODES) {
        int d = 0;
        #pragma unroll 16
        for (int sl = 0; sl < HSLICES; ++sl) d += g_degp[sl * N_NODES + t];
        g_dis[t] = (d > 0) ? rsqrtf((float)d) : 0.f;
    }
}

// ---- 3) edge scatter in projected space, LDS-privatized ----
// 128 blocks: khalf = bx>>6 (k in [khalf*5,khalf*5+5)), slice = bx&63 (1024 edges).
__global__ __launch_bounds__(256) void k_scatter(const int* __restrict__ ei) {
    __shared__ float zl[N_NODES * 5];            // 40 KB
    int khalf  = blockIdx.x >> 6;
    int bslice = blockIdx.x & (ZSLICES - 1);
    float4* zl4 = (float4*)zl;
    #pragma unroll
    for (int t = threadIdx.x; t < N_NODES * 5 / 4; t += 256)
        zl4[t] = make_float4(0.f, 0.f, 0.f, 0.f);
    __syncthreads();
    int base = bslice * (NEDGE / ZSLICES);
    #pragma unroll
    for (int u = 0; u < NEDGE / ZSLICES / 256; ++u) {
        int e = base + u * 256 + threadIdx.x;
        int r = ei[e], c = ei[NEDGE + e];
        float w = -g_dis[r] * g_dis[c];          // 0 if either deg==0
        const float* y1 = g_y + r * 20 + 10 + khalf * 5;
        float* zz = zl + c * 5;
        #pragma unroll
        for (int kk = 0; kk < 5; ++kk) atomicAdd(&zz[kk], w * y1[kk]);
    }
    __syncthreads();
    float4* dst = (float4*)(g_zp + ((size_t)khalf * ZSLICES + bslice) * (N_NODES * 5));
    #pragma unroll
    for (int t = threadIdx.x; t < N_NODES * 5 / 4; t += 256) dst[t] = zl4[t];
}

// ---- 4) coalesced z-partial reduction -> g_z[node][k] ----
__global__ __launch_bounds__(256) void k_zred() {
    int t = blockIdx.x * 256 + threadIdx.x;      // 80 blocks -> t < 20480
    int khalf = t / (N_NODES * 5);
    int rem   = t % (N_NODES * 5);
    float s = 0.f;
    #pragma unroll 16
    for (int sl = 0; sl < ZSLICES; ++sl)
        s += g_zp[((size_t)khalf * ZSLICES + sl) * (N_NODES * 5) + rem];
    int i = rem / 5, kk = rem - i * 5;
    g_z[i * 10 + khalf * 5 + kk] = s;
}

// ---- 5) epilogue: relu(y0+z+b) @ Wf + log_softmax ----
__global__ __launch_bounds__(256) void k_final(const float* __restrict__ b,
                                               const float* __restrict__ Wf,
                                               const float* __restrict__ bfv,
                                               float* __restrict__ out) {
    int i = blockIdx.x * 256 + threadIdx.x;      // grid == N_NODES exactly
    float h[G1];
    #pragma unroll
    for (int k = 0; k < G1; ++k)
        h[k] = fmaxf(g_y[i * 20 + k] + g_z[i * 10 + k] + b[k], 0.f);
    float lo[NCLS];
    #pragma unroll
    for (int c = 0; c < NCLS; ++c) lo[c] = bfv[c];
    #pragma unroll
    for (int k = 0; k < G1; ++k) {
        float hk = h[k];
        #pragma unroll
        for (int c = 0; c < NCLS; ++c) lo[c] += hk * Wf[k * NCLS + c];
    }
    float m = lo[0];
    #pragma unroll
    for (int c = 1; c < NCLS; ++c) m = fmaxf(m, lo[c]);
    float s = 0.f;
    #pragma unroll
    for (int c = 0; c < NCLS; ++c) s += expf(lo[c] - m);
    float ls = logf(s);
    #pragma unroll
    for (int c = 0; c < NCLS; ++c) out[i * NCLS + c] = lo[c] - m - ls;
}

extern "C" void kernel_launch(void* const* d_in, const int* in_sizes, int n_in,
                              void* d_out, int out_size, void* d_ws, size_t ws_size,
                              hipStream_t stream) {
    const float* x   = (const float*)d_in[0];
    const int*   ei  = (const int*)d_in[1];
    const float* W0  = (const float*)d_in[2];
    const float* W1  = (const float*)d_in[3];
    const float* b   = (const float*)d_in[4];
    const float* Wf  = (const float*)d_in[5];
    const float* bfv = (const float*)d_in[6];
    float* out = (float*)d_out;

    k_gemm<<<dim3(JCHUNKS, N_NODES / 256), 256, 0, stream>>>(x, W0, W1, ei);
    k_reduce<<<(N_NODES * 20) / 256, 256, 0, stream>>>();
    k_scatter<<<2 * ZSLICES, 256, 0, stream>>>(ei);
    k_zred<<<(N_NODES * G1) / 256, 256, 0, stream>>>();
    k_final<<<N_NODES / 256, 256, 0, stream>>>(b, Wf, bfv, out);
}